// Round 8
// baseline (425.027 us; speedup 1.0000x reference)
//
#include <hip/hip_runtime.h>
#include <cstdint>
#include <cstddef>

#define M_DIM 8192
#define N_DIM 4096
#define K_DIM 4096

// fallback-path tile (128x128, verified)
#define BM 128
#define BN 128
#define BK 128

// fast-path tile
#define BM2 256
#define BN2 256
#define BK2 128
#define NKT (K_DIM / BK2)   // 32

typedef int int32x4  __attribute__((ext_vector_type(4)));
typedef int int32x16 __attribute__((ext_vector_type(16)));

// ws layout:
//   int32 header (64 KB):
//     [0] = flagA (1 -> source already packed int8, 0 -> widened int32)
//     [1] = flagB
//     [16 .. 16+N)      qb (shifted bias)
//     [16+N .. 16+2N)   int_scale
//     [16+2N .. 16+3N)  frac_bits
//   byte 65536:           A8  (M*K int8)  (used when flagA==0)
//   byte 65536 + M*K:     W8  (N*K int8)  (used when flagB==0)

typedef __attribute__((address_space(1))) const void* gas_cptr;
typedef __attribute__((address_space(3))) void* las_ptr;

__device__ __forceinline__ void async_copy16(const void* g, void* l) {
    __builtin_amdgcn_global_load_lds((gas_cptr)g, (las_ptr)l, 16, 0, 0);
}

__device__ __forceinline__ int32x4 pack16(const int* p) {
    const int32x4* v = (const int32x4*)p;
    int32x4 w0 = v[0], w1 = v[1], w2 = v[2], w3 = v[3];
    int32x4 r;
    r.x = (w0.x & 0xFF) | ((w0.y & 0xFF) << 8) | ((w0.z & 0xFF) << 16) | (w0.w << 24);
    r.y = (w1.x & 0xFF) | ((w1.y & 0xFF) << 8) | ((w1.z & 0xFF) << 16) | (w1.w << 24);
    r.z = (w2.x & 0xFF) | ((w2.y & 0xFF) << 8) | ((w2.z & 0xFF) << 16) | (w2.w << 24);
    r.w = (w3.x & 0xFF) | ((w3.y & 0xFF) << 8) | ((w3.z & 0xFF) << 16) | (w3.w << 24);
    return r;
}

__global__ void ql_detect_kernel(const int* a, const int* b, int* ws) {
    int t = threadIdx.x;  // 64 threads
    int fa = 0, fb = 0;
    for (int i = t; i < 4096; i += 64) {
        int va = a[i]; if (va > 127 || va < -128) fa = 1;
        int vb = b[i]; if (vb > 127 || vb < -128) fb = 1;
    }
    unsigned long long ba = __ballot(fa);
    unsigned long long bb = __ballot(fb);
    if (t == 0) { ws[0] = ba ? 1 : 0; ws[1] = bb ? 1 : 0; }
}

// Merged pack + W-prep: block < PACK_WBLK handles exactly one W row (1024
// packed dwords) — packs it AND computes rowsum + requant params inline.
// Blocks >= PACK_WBLK pack the A segment. Early-exit per segment when packed.
#define PACK_WBLK 4096   // = N_DIM rows
#define PACK_ABLK 8192   // = M*K/4/1024
__global__ __launch_bounds__(256)
void ql_pack2_kernel(const void* wsrc, int* wdst, const void* asrc, int* adst,
                     const int* qbias, const float* wscale, int* ws) {
    __shared__ int red[4];
    const int fA = __builtin_amdgcn_readfirstlane(ws[0]);
    const int fW = __builtin_amdgcn_readfirstlane(ws[1]);
    const int bid = blockIdx.x;
    const int tid = threadIdx.x;
    if (bid < PACK_WBLK) {
        if (fW) return;                      // W already int8; prep8 handles params
        const int n = bid;                   // W row index
        const int32x4* src = (const int32x4*)wsrc + (size_t)n * 1024;
        int* dst = wdst + (size_t)n * 1024;
        int s = 0;
#pragma unroll
        for (int k = 0; k < 4; ++k) {
            const int i = k * 256 + tid;
            int32x4 v = src[i];
            s += v.x + v.y + v.z + v.w;
            dst[i] = (v.x & 0xFF) | ((v.y & 0xFF) << 8) | ((v.z & 0xFF) << 16) | (v.w << 24);
        }
#pragma unroll
        for (int off = 32; off > 0; off >>= 1) s += __shfl_down(s, off, 64);
        if ((tid & 63) == 0) red[tid >> 6] = s;
        __syncthreads();
        if (tid == 0) {
            const int st = red[0] + red[1] + red[2] + red[3];
            ws[16 + n] = qbias[n] + 3 * st;                      // qbias - rowsum*Zin
            float folded = (0.05f * wscale[n]) / 0.1f;           // in (0,1)
            int fbits = (int)(7.0f - ceilf(log2f(folded)));
            int isc = (int)rintf(folded * exp2f((float)fbits));
            ws[16 + N_DIM + n] = isc;
            ws[16 + 2 * N_DIM + n] = fbits;
        }
    } else {
        if (fA) return;
        const long base = (long)(bid - PACK_WBLK) * 1024;
        const int32x4* src = (const int32x4*)asrc + base;
        int* dst = adst + base;
#pragma unroll
        for (int k = 0; k < 4; ++k) {
            const int i = k * 256 + tid;
            int32x4 v = src[i];
            dst[i] = (v.x & 0xFF) | ((v.y & 0xFF) << 8) | ((v.z & 0xFF) << 16) | (v.w << 24);
        }
    }
}

// Fast-path prep: only needed when W arrived already-packed int8.
__global__ void ql_prep8_kernel(const void* worig, const int* qbias,
                                const float* wscale, int* ws) {
    const int fb = __builtin_amdgcn_readfirstlane(ws[1]);
    if (!fb) return;                         // pack already wrote the params

    const int lane = threadIdx.x & 63;
    const int wid  = threadIdx.x >> 6;
    const int n = blockIdx.x * 4 + wid;

    const int32x4* row = (const int32x4*)((const int8_t*)worig + (size_t)n * K_DIM);
    int s = 0;
    for (int c = lane; c < K_DIM / 16; c += 64) {
        int32x4 v = row[c];
#pragma unroll
        for (int j = 0; j < 4; ++j) {
            int w = (j == 0) ? v.x : (j == 1) ? v.y : (j == 2) ? v.z : v.w;
            s += (int)(int8_t)(w) + (int)(int8_t)(w >> 8)
               + (int)(int8_t)(w >> 16) + (w >> 24);
        }
    }
#pragma unroll
    for (int off = 32; off > 0; off >>= 1) s += __shfl_down(s, off, 64);

    if (lane == 0) {
        ws[16 + n] = qbias[n] + 3 * s;                       // qbias - rowsum*Zin, Zin=-3
        float folded = (0.05f * wscale[n]) / 0.1f;           // in (0,1)
        int fbits = (int)(7.0f - ceilf(log2f(folded)));
        int isc = (int)rintf(folded * exp2f((float)fbits));  // nearest-even == np.round
        ws[16 + N_DIM + n] = isc;
        ws[16 + 2 * N_DIM + n] = fbits;
    }
}

// Fallback prep (ws too small): reads original W, flag-based.
__global__ void ql_prep_kernel(const void* wptr, const int* qbias,
                               const float* wscale, int* ws) {
    const int lane = threadIdx.x & 63;
    const int wid  = threadIdx.x >> 6;
    const int n = blockIdx.x * 4 + wid;
    const int b8 = __builtin_amdgcn_readfirstlane(ws[1]);

    int s = 0;
    if (b8) {
        const int32x4* row = (const int32x4*)((const int8_t*)wptr + (size_t)n * K_DIM);
        for (int c = lane; c < K_DIM / 16; c += 64) {
            int32x4 v = row[c];
#pragma unroll
            for (int j = 0; j < 4; ++j) {
                int w = (j == 0) ? v.x : (j == 1) ? v.y : (j == 2) ? v.z : v.w;
                s += (int)(int8_t)(w) + (int)(int8_t)(w >> 8)
                   + (int)(int8_t)(w >> 16) + (w >> 24);
            }
        }
    } else {
        const int32x4* row = (const int32x4*)((const int*)wptr + (size_t)n * K_DIM);
        for (int c = lane; c < K_DIM / 4; c += 64) {
            int32x4 v = row[c];
            s += v.x + v.y + v.z + v.w;
        }
    }
#pragma unroll
    for (int off = 32; off > 0; off >>= 1) s += __shfl_down(s, off, 64);

    if (lane == 0) {
        ws[16 + n] = qbias[n] + 3 * s;
        float folded = (0.05f * wscale[n]) / 0.1f;
        int fbits = (int)(7.0f - ceilf(log2f(folded)));
        int isc = (int)rintf(folded * exp2f((float)fbits));
        ws[16 + N_DIM + n] = isc;
        ws[16 + 2 * N_DIM + n] = fbits;
    }
}

// Fallback epilogue (128x128 path): requantize acc tile and store int32.
__device__ __forceinline__ void ql_epilogue(int32x4 acc[4][4], const int* ws,
                                            int* out, int bm, int bn,
                                            int wm, int wn, int qm, int qh) {
    const int* qb  = ws + 16;
    const int* isc = ws + 16 + N_DIM;
    const int* fbt = ws + 16 + 2 * N_DIM;
#pragma unroll
    for (int j = 0; j < 4; ++j) {
        const int n_g = bn * BN + wn + j * 16 + qm;
        const int b0 = qb[n_g];
        const int s0 = isc[n_g];
        const int f0 = fbt[n_g];
#pragma unroll
        for (int i = 0; i < 4; ++i) {
            const int m_base = bm * BM + wm + i * 16 + qh * 4;
#pragma unroll
            for (int r = 0; r < 4; ++r) {
                int v = ((r == 0) ? acc[i][j].x : (r == 1) ? acc[i][j].y
                        : (r == 2) ? acc[i][j].z : acc[i][j].w) + b0;
                long long p = (long long)v * (long long)s0;
                int o = (int)(p >> f0) - 5;            // + OUTPUT_ZERO_POINT (-5)
                o = o < -128 ? -128 : (o > 127 ? 127 : o);
                out[(size_t)(m_base + r) * N_DIM + n_g] = o;
            }
        }
    }
}

// ---- fast path: 256x256 GEMM, 32x32x32 i8, 4 waves x (128x128 each) ----
// Rationale (R7 post-mortem): with 8 waves x (128x64), LDS read traffic was
// 192 ds_read_b128/tile (~2300cy) + 600cy writes, fully serialized with the
// 2340cy MFMA floor (measured 5078cy/tile). 4 waves x square 128x128 tiles cut
// duplication: 32 reads/wave x 4 = 128/tile (~1536cy) < MFMA floor.
// Per-kc software pipeline: read kc+1's 8 frags, then 16 register-only MFMAs
// on kc — LDS services next batch under the MFMA block (1 wave/SIMD, ILP-only).
// LDS geometry: proven zero-conflict (R3/R4): 128-B rows, 8 chunks,
// phys = c ^ f(row), f(row) = (row&7) ^ ((row>>3)&3); stage pre-applies f.
// Schedule: R4's proven best — stage early inside tile body, ONE __syncthreads.

#define TILE4(BUF, TT, DOST) do { \
    _Pragma("unroll") for (int i = 0; i < 4; ++i) af[0][i] = LA[BUF][baseAe[0] + i * 256]; \
    _Pragma("unroll") for (int j = 0; j < 4; ++j) bf[0][j] = LB[BUF][baseBe[0] + j * 256]; \
    if (DOST) { \
        _Pragma("unroll") for (int h = 0; h < 8; ++h) { \
            async_copy16(gA + (size_t)((TT) + 1) * 128 + (size_t)h * 131072, \
                         &LA[(BUF) ^ 1][h * 256 + t]); \
            async_copy16(gB + (size_t)((TT) + 1) * 128 + (size_t)h * 131072, \
                         &LB[(BUF) ^ 1][h * 256 + t]); \
        } \
    } \
    _Pragma("unroll") for (int kc = 0; kc < 4; ++kc) { \
        if (kc < 3) { \
            _Pragma("unroll") for (int i = 0; i < 4; ++i) \
                af[kc + 1][i] = LA[BUF][baseAe[kc + 1] + i * 256]; \
            _Pragma("unroll") for (int j = 0; j < 4; ++j) \
                bf[kc + 1][j] = LB[BUF][baseBe[kc + 1] + j * 256]; \
        } \
        __builtin_amdgcn_s_setprio(1); \
        _Pragma("unroll") for (int i = 0; i < 4; ++i) \
        _Pragma("unroll") for (int j = 0; j < 4; ++j) \
            acc[i][j] = __builtin_amdgcn_mfma_i32_32x32x32_i8( \
                af[kc][i], bf[kc][j], acc[i][j], 0, 0, 0); \
        __builtin_amdgcn_s_setprio(0); \
    } \
    __syncthreads(); \
} while (0)

__global__ __launch_bounds__(256, 1)
void ql_gemm8_kernel(const void* a0, const int8_t* a8,
                     const void* b0, const int8_t* w8,
                     const int* ws, int* out) {
    __shared__ int32x4 LA[2][2048];   // 2 x 32 KB
    __shared__ int32x4 LB[2][2048];   // total 128 KB

    const int fa = __builtin_amdgcn_readfirstlane(ws[0]);
    const int fb = __builtin_amdgcn_readfirstlane(ws[1]);
    const int8_t* aptr = fa ? (const int8_t*)a0 : a8;
    const int8_t* bptr = fb ? (const int8_t*)b0 : w8;

    const int t    = threadIdx.x;     // 256 threads = 4 waves
    const int lane = t & 63;
    const int wid  = t >> 6;          // 0..3
    const int wr   = wid >> 1;        // 0..1  M-half (128 rows)
    const int wc   = wid & 1;         // 0..1  N-half (128 cols)
    const int l31  = lane & 31;
    const int hi   = lane >> 5;

    // XCD-chunked bijective swizzle (nwg = 512 = 8 XCD x 64)
    const int flat = blockIdx.y * gridDim.x + blockIdx.x;   // 0..511
    const int xcd  = flat & 7;
    const int lid  = flat >> 3;
    const int g    = lid >> 5;
    const int r    = lid & 31;
    const int bm   = xcd * 4 + g * 2 + (r & 1);   // 0..31
    const int bn   = r >> 1;                      // 0..15

    const int arow0 = bm * BM2;
    const int brow0 = bn * BN2;

    // LDS frag bases (units of int32x4). phys = logical ^ f(row),
    // f(row) = (row&7) ^ ((row>>3)&3); frag rows are base(mult of 32) + l31
    // -> f = (lane&7) ^ ((l31>>3)&3).
    const int fr = (lane & 7) ^ ((l31 >> 3) & 3);
    int baseAe[4], baseBe[4];
#pragma unroll
    for (int kc = 0; kc < 4; ++kc) {
        const int phys = (kc * 2 + hi) ^ fr;
        baseAe[kc] = (wr * 128 + l31) * 8 + phys;
        baseBe[kc] = (wc * 128 + l31) * 8 + phys;
    }

    // Stage source pre-swizzle: thread t writes phys chunk (t&7) of row
    // h*32 + (t>>3); logical col = (t&7) ^ f(row) = (t&7)^((t>>3)&7)^((t>>6)&3).
    const int colg = (t & 7) ^ ((t >> 3) & 7) ^ ((t >> 6) & 3);
    const int8_t* gA = aptr + (size_t)(arow0 + (t >> 3)) * K_DIM + colg * 16;
    const int8_t* gB = bptr + (size_t)(brow0 + (t >> 3)) * K_DIM + colg * 16;

    int32x16 acc[4][4] = {};
    int32x4 af[4][4], bf[4][4];

    // prologue: stage T0 -> buf0 (16 loads/thread)
#pragma unroll
    for (int h = 0; h < 8; ++h) {
        async_copy16(gA + (size_t)h * 131072, &LA[0][h * 256 + t]);
        async_copy16(gB + (size_t)h * 131072, &LB[0][h * 256 + t]);
    }
    __syncthreads();

#pragma unroll 1
    for (int T = 0; T < NKT - 2; T += 2) {
        TILE4(0, T, true);
        TILE4(1, T + 1, true);
    }
    TILE4(0, NKT - 2, true);
    TILE4(1, NKT - 1, false);

    // epilogue: requantize + non-temporal store
    // (C/D map: col=lane&31, row=(reg&3)+8*(reg>>2)+4*hi)
    const int* qb  = ws + 16;
    const int* isc = ws + 16 + N_DIM;
    const int* fbt = ws + 16 + 2 * N_DIM;
#pragma unroll
    for (int j = 0; j < 4; ++j) {
        const int n_g = bn * BN2 + wc * 128 + j * 32 + l31;
        const int b0r = qb[n_g];
        const int s0r = isc[n_g];
        const int f0r = fbt[n_g];
#pragma unroll
        for (int i = 0; i < 4; ++i) {
            const int m0 = bm * BM2 + wr * 128 + i * 32 + hi * 4;
#pragma unroll
            for (int reg = 0; reg < 16; ++reg) {
                const int row = (reg & 3) + 8 * (reg >> 2);
                int v = acc[i][j][reg] + b0r;
                long long p = (long long)v * (long long)s0r;
                int o = (int)(p >> f0r) - 5;           // + OUTPUT_ZERO_POINT (-5)
                o = o < -128 ? -128 : (o > 127 ? 127 : o);
                __builtin_nontemporal_store(o, &out[(size_t)(m0 + row) * N_DIM + n_g]);
            }
        }
    }
}

// Fallback (ws too small): verified 128x128 kernel, packs in-loop.
__global__ __launch_bounds__(256)
void ql_gemm_fb_kernel(const void* aptr, const void* bptr, const int* ws, int* out) {
    __shared__ int32x4 Als[BM * BK / 16];
    __shared__ int32x4 Bls[BN * BK / 16];

    const int a8 = __builtin_amdgcn_readfirstlane(ws[0]);
    const int b8 = __builtin_amdgcn_readfirstlane(ws[1]);

    const int t    = threadIdx.x;
    const int lane = t & 63;
    const int wid  = t >> 6;
    const int bn = blockIdx.x;
    const int bm = blockIdx.y;

    const int wm = (wid >> 1) * 64;
    const int wn = (wid & 1) * 64;
    const int qm = lane & 15;
    const int qh = lane >> 4;

    int32x4 acc[4][4] = {};

    for (int kt = 0; kt < K_DIM / BK; ++kt) {
        __syncthreads();
        const int k0 = kt * BK;
#pragma unroll
        for (int r = 0; r < 4; ++r) {
            const int c    = r * 256 + t;
            const int row  = c >> 3;
            const int colg = (c & 7) ^ (row & 7);
            const size_t offA = (size_t)(bm * BM + row) * K_DIM + k0 + colg * 16;
            const size_t offB = (size_t)(bn * BN + row) * K_DIM + k0 + colg * 16;
            if (a8) async_copy16((const int8_t*)aptr + offA, &Als[c]);
            else    Als[c] = pack16((const int*)aptr + offA);
            if (b8) async_copy16((const int8_t*)bptr + offB, &Bls[c]);
            else    Bls[c] = pack16((const int*)bptr + offB);
        }
        __syncthreads();

#pragma unroll
        for (int s = 0; s < 2; ++s) {
            const int colk = s * 4 + qh;
            int32x4 af[4], bf[4];
#pragma unroll
            for (int i = 0; i < 4; ++i) {
                const int ra = wm + i * 16 + qm;
                const int rb = wn + i * 16 + qm;
                af[i] = Als[ra * 8 + (colk ^ (ra & 7))];
                bf[i] = Bls[rb * 8 + (colk ^ (rb & 7))];
            }
#pragma unroll
            for (int i = 0; i < 4; ++i)
#pragma unroll
                for (int j = 0; j < 4; ++j)
                    acc[i][j] = __builtin_amdgcn_mfma_i32_16x16x64_i8(
                        af[i], bf[j], acc[i][j], 0, 0, 0);
        }
    }
    ql_epilogue(acc, ws, out, bm, bn, wm, wn, qm, qh);
}

extern "C" void kernel_launch(void* const* d_in, const int* in_sizes, int n_in,
                              void* d_out, int out_size, void* d_ws, size_t ws_size,
                              hipStream_t stream) {
    const void* qin    = d_in[0];
    const void* qwt    = d_in[1];
    const int* qbias   = (const int*)d_in[2];
    const float* wscal = (const float*)d_in[3];
    int* ws  = (int*)d_ws;
    int* out = (int*)d_out;

    hipLaunchKernelGGL(ql_detect_kernel, dim3(1), dim3(64), 0, stream,
                       (const int*)qin, (const int*)qwt, ws);

    const size_t need = 65536 + (size_t)M_DIM * K_DIM + (size_t)N_DIM * K_DIM;
    if (ws_size >= need) {
        int8_t* a8 = (int8_t*)d_ws + 65536;
        int8_t* w8 = a8 + (size_t)M_DIM * K_DIM;
        hipLaunchKernelGGL(ql_pack2_kernel, dim3(PACK_WBLK + PACK_ABLK), dim3(256),
                           0, stream, qwt, (int*)w8, qin, (int*)a8, qbias, wscal, ws);
        hipLaunchKernelGGL(ql_prep8_kernel, dim3(N_DIM / 4), dim3(256), 0, stream,
                           qwt, qbias, wscal, ws);
        hipLaunchKernelGGL(ql_gemm8_kernel, dim3(N_DIM / BN2, M_DIM / BM2), dim3(256),
                           0, stream, qin, a8, qwt, w8, ws, out);
    } else {
        hipLaunchKernelGGL(ql_prep_kernel, dim3(N_DIM / 4), dim3(256), 0, stream,
                           qwt, qbias, wscal, ws);
        hipLaunchKernelGGL(ql_gemm_fb_kernel, dim3(N_DIM / BN, M_DIM / BM), dim3(256), 0, stream,
                           qin, qwt, ws, out);
    }
}

// Round 10
// 416.012 us; speedup vs baseline: 1.0217x; 1.0217x over previous
//
#include <hip/hip_runtime.h>
#include <cstdint>
#include <cstddef>

#define M_DIM 8192
#define N_DIM 4096
#define K_DIM 4096

// fallback-path tile (128x128, verified)
#define BM 128
#define BN 128
#define BK 128

// fast-path tile
#define BM2 256
#define BN2 256
#define BK2 128
#define NKT (K_DIM / BK2)   // 32

typedef int int32x4  __attribute__((ext_vector_type(4)));
typedef int int32x16 __attribute__((ext_vector_type(16)));

// ws layout:
//   int32 header (64 KB):
//     [0] = flagA (1 -> source already packed int8, 0 -> widened int32)
//     [1] = flagB
//     [16 .. 16+N)      qb (shifted bias)
//     [16+N .. 16+2N)   int_scale
//     [16+2N .. 16+3N)  frac_bits
//   byte 65536:           A8  (M*K int8)  (used when flagA==0)
//   byte 65536 + M*K:     W8  (N*K int8)  (used when flagB==0)

typedef __attribute__((address_space(1))) const void* gas_cptr;
typedef __attribute__((address_space(3))) void* las_ptr;

__device__ __forceinline__ void async_copy16(const void* g, void* l) {
    __builtin_amdgcn_global_load_lds((gas_cptr)g, (las_ptr)l, 16, 0, 0);
}

__device__ __forceinline__ int32x4 pack16(const int* p) {
    const int32x4* v = (const int32x4*)p;
    int32x4 w0 = v[0], w1 = v[1], w2 = v[2], w3 = v[3];
    int32x4 r;
    r.x = (w0.x & 0xFF) | ((w0.y & 0xFF) << 8) | ((w0.z & 0xFF) << 16) | (w0.w << 24);
    r.y = (w1.x & 0xFF) | ((w1.y & 0xFF) << 8) | ((w1.z & 0xFF) << 16) | (w1.w << 24);
    r.z = (w2.x & 0xFF) | ((w2.y & 0xFF) << 8) | ((w2.z & 0xFF) << 16) | (w2.w << 24);
    r.w = (w3.x & 0xFF) | ((w3.y & 0xFF) << 8) | ((w3.z & 0xFF) << 16) | (w3.w << 24);
    return r;
}

__global__ void ql_detect_kernel(const int* a, const int* b, int* ws) {
    int t = threadIdx.x;  // 64 threads
    int fa = 0, fb = 0;
    for (int i = t; i < 4096; i += 64) {
        int va = a[i]; if (va > 127 || va < -128) fa = 1;
        int vb = b[i]; if (vb > 127 || vb < -128) fb = 1;
    }
    unsigned long long ba = __ballot(fa);
    unsigned long long bb = __ballot(fb);
    if (t == 0) { ws[0] = ba ? 1 : 0; ws[1] = bb ? 1 : 0; }
}

// Merged pack + W-prep: block < PACK_WBLK handles exactly one W row (1024
// packed dwords) — packs it AND computes rowsum + requant params inline.
// Blocks >= PACK_WBLK pack the A segment. Early-exit per segment when packed.
#define PACK_WBLK 4096   // = N_DIM rows
#define PACK_ABLK 8192   // = M*K/4/1024
__global__ __launch_bounds__(256)
void ql_pack2_kernel(const void* wsrc, int* wdst, const void* asrc, int* adst,
                     const int* qbias, const float* wscale, int* ws) {
    __shared__ int red[4];
    const int fA = __builtin_amdgcn_readfirstlane(ws[0]);
    const int fW = __builtin_amdgcn_readfirstlane(ws[1]);
    const int bid = blockIdx.x;
    const int tid = threadIdx.x;
    if (bid < PACK_WBLK) {
        if (fW) return;                      // W already int8; prep8 handles params
        const int n = bid;                   // W row index
        const int32x4* src = (const int32x4*)wsrc + (size_t)n * 1024;
        int* dst = wdst + (size_t)n * 1024;
        int s = 0;
#pragma unroll
        for (int k = 0; k < 4; ++k) {
            const int i = k * 256 + tid;
            int32x4 v = src[i];
            s += v.x + v.y + v.z + v.w;
            dst[i] = (v.x & 0xFF) | ((v.y & 0xFF) << 8) | ((v.z & 0xFF) << 16) | (v.w << 24);
        }
#pragma unroll
        for (int off = 32; off > 0; off >>= 1) s += __shfl_down(s, off, 64);
        if ((tid & 63) == 0) red[tid >> 6] = s;
        __syncthreads();
        if (tid == 0) {
            const int st = red[0] + red[1] + red[2] + red[3];
            ws[16 + n] = qbias[n] + 3 * st;                      // qbias - rowsum*Zin
            float folded = (0.05f * wscale[n]) / 0.1f;           // in (0,1)
            int fbits = (int)(7.0f - ceilf(log2f(folded)));
            int isc = (int)rintf(folded * exp2f((float)fbits));
            ws[16 + N_DIM + n] = isc;
            ws[16 + 2 * N_DIM + n] = fbits;
        }
    } else {
        if (fA) return;
        const long base = (long)(bid - PACK_WBLK) * 1024;
        const int32x4* src = (const int32x4*)asrc + base;
        int* dst = adst + base;
#pragma unroll
        for (int k = 0; k < 4; ++k) {
            const int i = k * 256 + tid;
            int32x4 v = src[i];
            dst[i] = (v.x & 0xFF) | ((v.y & 0xFF) << 8) | ((v.z & 0xFF) << 16) | (v.w << 24);
        }
    }
}

// Fast-path prep: only needed when W arrived already-packed int8.
__global__ void ql_prep8_kernel(const void* worig, const int* qbias,
                                const float* wscale, int* ws) {
    const int fb = __builtin_amdgcn_readfirstlane(ws[1]);
    if (!fb) return;                         // pack already wrote the params

    const int lane = threadIdx.x & 63;
    const int wid  = threadIdx.x >> 6;
    const int n = blockIdx.x * 4 + wid;

    const int32x4* row = (const int32x4*)((const int8_t*)worig + (size_t)n * K_DIM);
    int s = 0;
    for (int c = lane; c < K_DIM / 16; c += 64) {
        int32x4 v = row[c];
#pragma unroll
        for (int j = 0; j < 4; ++j) {
            int w = (j == 0) ? v.x : (j == 1) ? v.y : (j == 2) ? v.z : v.w;
            s += (int)(int8_t)(w) + (int)(int8_t)(w >> 8)
               + (int)(int8_t)(w >> 16) + (w >> 24);
        }
    }
#pragma unroll
    for (int off = 32; off > 0; off >>= 1) s += __shfl_down(s, off, 64);

    if (lane == 0) {
        ws[16 + n] = qbias[n] + 3 * s;                       // qbias - rowsum*Zin, Zin=-3
        float folded = (0.05f * wscale[n]) / 0.1f;           // in (0,1)
        int fbits = (int)(7.0f - ceilf(log2f(folded)));
        int isc = (int)rintf(folded * exp2f((float)fbits));  // nearest-even == np.round
        ws[16 + N_DIM + n] = isc;
        ws[16 + 2 * N_DIM + n] = fbits;
    }
}

// Fallback prep (ws too small): reads original W, flag-based.
__global__ void ql_prep_kernel(const void* wptr, const int* qbias,
                               const float* wscale, int* ws) {
    const int lane = threadIdx.x & 63;
    const int wid  = threadIdx.x >> 6;
    const int n = blockIdx.x * 4 + wid;
    const int b8 = __builtin_amdgcn_readfirstlane(ws[1]);

    int s = 0;
    if (b8) {
        const int32x4* row = (const int32x4*)((const int8_t*)wptr + (size_t)n * K_DIM);
        for (int c = lane; c < K_DIM / 16; c += 64) {
            int32x4 v = row[c];
#pragma unroll
            for (int j = 0; j < 4; ++j) {
                int w = (j == 0) ? v.x : (j == 1) ? v.y : (j == 2) ? v.z : v.w;
                s += (int)(int8_t)(w) + (int)(int8_t)(w >> 8)
                   + (int)(int8_t)(w >> 16) + (w >> 24);
            }
        }
    } else {
        const int32x4* row = (const int32x4*)((const int*)wptr + (size_t)n * K_DIM);
        for (int c = lane; c < K_DIM / 4; c += 64) {
            int32x4 v = row[c];
            s += v.x + v.y + v.z + v.w;
        }
    }
#pragma unroll
    for (int off = 32; off > 0; off >>= 1) s += __shfl_down(s, off, 64);

    if (lane == 0) {
        ws[16 + n] = qbias[n] + 3 * s;
        float folded = (0.05f * wscale[n]) / 0.1f;
        int fbits = (int)(7.0f - ceilf(log2f(folded)));
        int isc = (int)rintf(folded * exp2f((float)fbits));
        ws[16 + N_DIM + n] = isc;
        ws[16 + 2 * N_DIM + n] = fbits;
    }
}

// Fallback epilogue (128x128 path): requantize acc tile and store int32.
__device__ __forceinline__ void ql_epilogue(int32x4 acc[4][4], const int* ws,
                                            int* out, int bm, int bn,
                                            int wm, int wn, int qm, int qh) {
    const int* qb  = ws + 16;
    const int* isc = ws + 16 + N_DIM;
    const int* fbt = ws + 16 + 2 * N_DIM;
#pragma unroll
    for (int j = 0; j < 4; ++j) {
        const int n_g = bn * BN + wn + j * 16 + qm;
        const int b0 = qb[n_g];
        const int s0 = isc[n_g];
        const int f0 = fbt[n_g];
#pragma unroll
        for (int i = 0; i < 4; ++i) {
            const int m_base = bm * BM + wm + i * 16 + qh * 4;
#pragma unroll
            for (int r = 0; r < 4; ++r) {
                int v = ((r == 0) ? acc[i][j].x : (r == 1) ? acc[i][j].y
                        : (r == 2) ? acc[i][j].z : acc[i][j].w) + b0;
                long long p = (long long)v * (long long)s0;
                int o = (int)(p >> f0) - 5;            // + OUTPUT_ZERO_POINT (-5)
                o = o < -128 ? -128 : (o > 127 ? 127 : o);
                out[(size_t)(m_base + r) * N_DIM + n_g] = o;
            }
        }
    }
}

// -- fast path: 256x256, 32x32x32 i8, 8-phase counted-vmcnt ring (R2 structure)
//    + PROVEN zero-conflict swizzle (R3/R4): phys = c ^ f(row),
//      f(row) = (row&7) ^ ((row>>3)&3); stage source pre-applies f.
// Per tile T (BUF = T&1), phases (each: reads; stage; s_barrier; MFMA; s_barrier):
//   ph1: read A-lo(8) + B-n0(4); stage (T+1).A1 -> LA[BUF^1]; quad(0,0)
//   ph2: read B-n1(4);           stage (T+1).B1 -> LB[BUF^1]; quad(0,1)
//   ph3: read A-hi(8);           stage (T+2).B0 -> LB[BUF];   quad(1,0)
//   ph4: (no reads);             stage (T+2).A0 -> LA[BUF];   quad(1,1)
// Hazards (deterministic, not latency-based): B0's readers (wc=0,1) finish by
// ph2's MFMA lgkm-wait, stage issued after ph2-closing barrier; A0's readers
// (wr=0 A-hi) finish by ph3's MFMA, stage after ph3-closing barrier.
// vmcnt(4) at tile top retires exactly tile T's 8 loads (ordering audited:
// carried [T.B0,T.A0] + prev-tile issued [T.A1,T.B1,(T+1).B0,(T+1).A0]);
// last tile vmcnt(0). No full drain in the main loop.

#define LOAD_AF(BUF, MH, DST) do { \
    _Pragma("unroll") for (int ml = 0; ml < 2; ++ml) \
    _Pragma("unroll") for (int kc = 0; kc < 4; ++kc) \
        DST[ml][kc] = LA[BUF][baseAe[kc] + (MH) * 512 + ml * 256]; \
} while (0)

#define LOAD_BF(BUF, NH, DST) do { \
    _Pragma("unroll") for (int kc = 0; kc < 4; ++kc) \
        DST[kc] = LB[BUF][baseBe[kc] + (NH) * 256]; \
} while (0)

#define MFMA_QUAD(MH, NH, AF, BF) do { \
    __builtin_amdgcn_s_setprio(1); \
    _Pragma("unroll") for (int kc = 0; kc < 4; ++kc) \
    _Pragma("unroll") for (int ml = 0; ml < 2; ++ml) \
        acc[(MH) * 2 + ml][NH] = __builtin_amdgcn_mfma_i32_32x32x32_i8( \
            AF[ml][kc], BF[kc], acc[(MH) * 2 + ml][NH], 0, 0, 0); \
    __builtin_amdgcn_s_setprio(0); \
} while (0)

#define STAGE_A(BUF, H, TT) do { \
    async_copy16(gA + (size_t)(TT) * 128 + (H) * 524288,          &LA[BUF][(H) * 1024 + t]); \
    async_copy16(gA + (size_t)(TT) * 128 + (H) * 524288 + 262144, &LA[BUF][(H) * 1024 + 512 + t]); \
} while (0)

#define STAGE_B(BUF, H, TT) do { \
    async_copy16(gB + (size_t)(TT) * 128 + (H) * 524288,          &LB[BUF][(H) * 1024 + t]); \
    async_copy16(gB + (size_t)(TT) * 128 + (H) * 524288 + 262144, &LB[BUF][(H) * 1024 + 512 + t]); \
} while (0)

#define TILE_BODY(BUF, TT, VMC) do { \
    asm volatile("s_waitcnt vmcnt(" #VMC ")" ::: "memory"); \
    __builtin_amdgcn_s_barrier(); \
    LOAD_AF(BUF, 0, afL); \
    LOAD_BF(BUF, 0, bf0); \
    if ((TT) + 1 < NKT) { STAGE_A(BUF ^ 1, 1, (TT) + 1); } \
    __builtin_amdgcn_s_barrier(); \
    MFMA_QUAD(0, 0, afL, bf0); \
    __builtin_amdgcn_s_barrier(); \
    LOAD_BF(BUF, 1, bf1); \
    if ((TT) + 1 < NKT) { STAGE_B(BUF ^ 1, 1, (TT) + 1); } \
    __builtin_amdgcn_s_barrier(); \
    MFMA_QUAD(0, 1, afL, bf1); \
    __builtin_amdgcn_s_barrier(); \
    LOAD_AF(BUF, 1, afH); \
    if ((TT) + 2 < NKT) { STAGE_B(BUF, 0, (TT) + 2); } \
    __builtin_amdgcn_s_barrier(); \
    MFMA_QUAD(1, 0, afH, bf0); \
    __builtin_amdgcn_s_barrier(); \
    if ((TT) + 2 < NKT) { STAGE_A(BUF, 0, (TT) + 2); } \
    __builtin_amdgcn_s_barrier(); \
    MFMA_QUAD(1, 1, afH, bf1); \
} while (0)

__global__ __launch_bounds__(512, 2)
void ql_gemm8_kernel(const void* a0, const int8_t* a8,
                     const void* b0, const int8_t* w8,
                     const int* ws, int* out) {
    __shared__ int32x4 LA[2][2048];   // 2 x 32 KB
    __shared__ int32x4 LB[2][2048];   // total 128 KB

    const int fa = __builtin_amdgcn_readfirstlane(ws[0]);
    const int fb = __builtin_amdgcn_readfirstlane(ws[1]);
    const int8_t* aptr = fa ? (const int8_t*)a0 : a8;
    const int8_t* bptr = fb ? (const int8_t*)b0 : w8;

    const int t    = threadIdx.x;     // 512 threads = 8 waves
    const int lane = t & 63;
    const int wid  = t >> 6;          // 0..7
    const int wr   = wid >> 2;        // 0..1  M-half (128 rows)
    const int wc   = wid & 3;         // 0..3  N-quarter (64 cols)
    const int l31  = lane & 31;
    const int hi   = lane >> 5;

    // XCD-chunked bijective swizzle (nwg = 512 = 8 XCD x 64)
    const int flat = blockIdx.y * gridDim.x + blockIdx.x;   // 0..511
    const int xcd  = flat & 7;
    const int lid  = flat >> 3;
    const int g    = lid >> 5;
    const int r    = lid & 31;
    const int bm   = xcd * 4 + g * 2 + (r & 1);   // 0..31
    const int bn   = r >> 1;                      // 0..15

    const int arow0 = bm * BM2;
    const int brow0 = bn * BN2;

    // LDS frag bases (units of int32x4). phys = logical ^ f(row),
    // f(row) = (row&7) ^ ((row>>3)&3). All frag-row offsets (wr*128, wc*64,
    // MH*64, ml*32, NH*32) are multiples of 32 -> f = (lane&7) ^ ((l31>>3)&3)
    // uniformly across MH/ml/NH.
    const int fr = (lane & 7) ^ ((l31 >> 3) & 3);
    int baseAe[4], baseBe[4];
#pragma unroll
    for (int kc = 0; kc < 4; ++kc) {
        const int phys = (kc * 2 + hi) ^ fr;
        baseAe[kc] = (wr * 128 + l31) * 8 + phys;
        baseBe[kc] = (wc * 64  + l31) * 8 + phys;
    }

    // Stage source pre-swizzle: thread t writes phys chunk (t&7) of row
    // H*128 + r*64 + (t>>3); logical col = (t&7) ^ f(row)
    //   = (t&7) ^ ((t>>3)&7) ^ ((t>>6)&3)   (H*16, r*8 terms vanish mod 4).
    const int colg = (t & 7) ^ ((t >> 3) & 7) ^ ((t >> 6) & 3);
    const int8_t* gA = aptr + (size_t)(arow0 + (t >> 3)) * K_DIM + colg * 16;
    const int8_t* gB = bptr + (size_t)(brow0 + (t >> 3)) * K_DIM + colg * 16;

    int32x16 acc[4][2] = {};
    int32x4 afL[2][4], afH[2][4], bf0[4], bf1[4];

    // prologue: T0 full tile, then T1.{B0,A0} (12 loads/thread outstanding)
    STAGE_A(0, 0, 0); STAGE_B(0, 0, 0);
    STAGE_A(0, 1, 0); STAGE_B(0, 1, 0);
    STAGE_B(1, 0, 1); STAGE_A(1, 0, 1);

#pragma unroll 1
    for (int T = 0; T < NKT - 2; T += 2) {
        TILE_BODY(0, T, 4);
        TILE_BODY(1, T + 1, 4);
    }
    TILE_BODY(0, NKT - 2, 4);
    TILE_BODY(1, NKT - 1, 0);

    // epilogue: requantize + non-temporal store
    // (C/D map: col=lane&31, row=(reg&3)+8*(reg>>2)+4*hi)
    const int* qb  = ws + 16;
    const int* isc = ws + 16 + N_DIM;
    const int* fbt = ws + 16 + 2 * N_DIM;
#pragma unroll
    for (int j = 0; j < 2; ++j) {
        const int n_g = bn * BN2 + wc * 64 + j * 32 + l31;
        const int b0r = qb[n_g];
        const int s0r = isc[n_g];
        const int f0r = fbt[n_g];
#pragma unroll
        for (int i = 0; i < 4; ++i) {
            const int m0 = bm * BM2 + wr * 128 + i * 32 + hi * 4;
#pragma unroll
            for (int reg = 0; reg < 16; ++reg) {
                const int row = (reg & 3) + 8 * (reg >> 2);
                int v = acc[i][j][reg] + b0r;
                long long p = (long long)v * (long long)s0r;
                int o = (int)(p >> f0r) - 5;           // + OUTPUT_ZERO_POINT (-5)
                o = o < -128 ? -128 : (o > 127 ? 127 : o);
                __builtin_nontemporal_store(o, &out[(size_t)(m0 + row) * N_DIM + n_g]);
            }
        }
    }
}

// Fallback (ws too small): verified 128x128 kernel, packs in-loop.
__global__ __launch_bounds__(256)
void ql_gemm_fb_kernel(const void* aptr, const void* bptr, const int* ws, int* out) {
    __shared__ int32x4 Als[BM * BK / 16];
    __shared__ int32x4 Bls[BN * BK / 16];

    const int a8 = __builtin_amdgcn_readfirstlane(ws[0]);
    const int b8 = __builtin_amdgcn_readfirstlane(ws[1]);

    const int t    = threadIdx.x;
    const int lane = t & 63;
    const int wid  = t >> 6;
    const int bn = blockIdx.x;
    const int bm = blockIdx.y;

    const int wm = (wid >> 1) * 64;
    const int wn = (wid & 1) * 64;
    const int qm = lane & 15;
    const int qh = lane >> 4;

    int32x4 acc[4][4] = {};

    for (int kt = 0; kt < K_DIM / BK; ++kt) {
        __syncthreads();
        const int k0 = kt * BK;
#pragma unroll
        for (int r = 0; r < 4; ++r) {
            const int c    = r * 256 + t;
            const int row  = c >> 3;
            const int colg = (c & 7) ^ (row & 7);
            const size_t offA = (size_t)(bm * BM + row) * K_DIM + k0 + colg * 16;
            const size_t offB = (size_t)(bn * BN + row) * K_DIM + k0 + colg * 16;
            if (a8) async_copy16((const int8_t*)aptr + offA, &Als[c]);
            else    Als[c] = pack16((const int*)aptr + offA);
            if (b8) async_copy16((const int8_t*)bptr + offB, &Bls[c]);
            else    Bls[c] = pack16((const int*)bptr + offB);
        }
        __syncthreads();

#pragma unroll
        for (int s = 0; s < 2; ++s) {
            const int colk = s * 4 + qh;
            int32x4 af[4], bf[4];
#pragma unroll
            for (int i = 0; i < 4; ++i) {
                const int ra = wm + i * 16 + qm;
                const int rb = wn + i * 16 + qm;
                af[i] = Als[ra * 8 + (colk ^ (ra & 7))];
                bf[i] = Bls[rb * 8 + (colk ^ (rb & 7))];
            }
#pragma unroll
            for (int i = 0; i < 4; ++i)
#pragma unroll
                for (int j = 0; j < 4; ++j)
                    acc[i][j] = __builtin_amdgcn_mfma_i32_16x16x64_i8(
                        af[i], bf[j], acc[i][j], 0, 0, 0);
        }
    }
    ql_epilogue(acc, ws, out, bm, bn, wm, wn, qm, qh);
}

extern "C" void kernel_launch(void* const* d_in, const int* in_sizes, int n_in,
                              void* d_out, int out_size, void* d_ws, size_t ws_size,
                              hipStream_t stream) {
    const void* qin    = d_in[0];
    const void* qwt    = d_in[1];
    const int* qbias   = (const int*)d_in[2];
    const float* wscal = (const float*)d_in[3];
    int* ws  = (int*)d_ws;
    int* out = (int*)d_out;

    hipLaunchKernelGGL(ql_detect_kernel, dim3(1), dim3(64), 0, stream,
                       (const int*)qin, (const int*)qwt, ws);

    const size_t need = 65536 + (size_t)M_DIM * K_DIM + (size_t)N_DIM * K_DIM;
    if (ws_size >= need) {
        int8_t* a8 = (int8_t*)d_ws + 65536;
        int8_t* w8 = a8 + (size_t)M_DIM * K_DIM;
        hipLaunchKernelGGL(ql_pack2_kernel, dim3(PACK_WBLK + PACK_ABLK), dim3(256),
                           0, stream, qwt, (int*)w8, qin, (int*)a8, qbias, wscal, ws);
        hipLaunchKernelGGL(ql_prep8_kernel, dim3(N_DIM / 4), dim3(256), 0, stream,
                           qwt, qbias, wscal, ws);
        hipLaunchKernelGGL(ql_gemm8_kernel, dim3(N_DIM / BN2, M_DIM / BM2), dim3(512),
                           0, stream, qin, a8, qwt, w8, ws, out);
    } else {
        hipLaunchKernelGGL(ql_prep_kernel, dim3(N_DIM / 4), dim3(256), 0, stream,
                           qwt, qbias, wscal, ws);
        hipLaunchKernelGGL(ql_gemm_fb_kernel, dim3(N_DIM / BN, M_DIM / BM), dim3(256), 0, stream,
                           qin, qwt, ws, out);
    }
}

// Round 11
// 415.187 us; speedup vs baseline: 1.0237x; 1.0020x over previous
//
#include <hip/hip_runtime.h>
#include <cstdint>
#include <cstddef>

#define M_DIM 8192
#define N_DIM 4096
#define K_DIM 4096

// fallback-path tile (128x128, verified)
#define BM 128
#define BN 128
#define BK 128

// fast-path tile
#define BM2 256
#define BN2 256
#define BK2 128
#define NKT (K_DIM / BK2)   // 32

typedef int int32x4  __attribute__((ext_vector_type(4)));
typedef int int32x16 __attribute__((ext_vector_type(16)));

// ws layout:
//   int32 header (64 KB):
//     [0] = flagA (1 -> source already packed int8, 0 -> widened int32)
//     [1] = flagB
//     [16 .. 16+N)      qb (shifted bias)
//     [16+N .. 16+2N)   int_scale
//     [16+2N .. 16+3N)  frac_bits
//   byte 65536:           A8  (M*K int8)  (used when flagA==0)
//   byte 65536 + M*K:     W8  (N*K int8)  (used when flagB==0)

typedef __attribute__((address_space(1))) const void* gas_cptr;
typedef __attribute__((address_space(3))) void* las_ptr;

__device__ __forceinline__ void async_copy16(const void* g, void* l) {
    __builtin_amdgcn_global_load_lds((gas_cptr)g, (las_ptr)l, 16, 0, 0);
}

__device__ __forceinline__ int32x4 pack16(const int* p) {
    const int32x4* v = (const int32x4*)p;
    int32x4 w0 = v[0], w1 = v[1], w2 = v[2], w3 = v[3];
    int32x4 r;
    r.x = (w0.x & 0xFF) | ((w0.y & 0xFF) << 8) | ((w0.z & 0xFF) << 16) | (w0.w << 24);
    r.y = (w1.x & 0xFF) | ((w1.y & 0xFF) << 8) | ((w1.z & 0xFF) << 16) | (w1.w << 24);
    r.z = (w2.x & 0xFF) | ((w2.y & 0xFF) << 8) | ((w2.z & 0xFF) << 16) | (w2.w << 24);
    r.w = (w3.x & 0xFF) | ((w3.y & 0xFF) << 8) | ((w3.z & 0xFF) << 16) | (w3.w << 24);
    return r;
}

__global__ void ql_detect_kernel(const int* a, const int* b, int* ws) {
    int t = threadIdx.x;  // 64 threads
    int fa = 0, fb = 0;
    for (int i = t; i < 4096; i += 64) {
        int va = a[i]; if (va > 127 || va < -128) fa = 1;
        int vb = b[i]; if (vb > 127 || vb < -128) fb = 1;
    }
    unsigned long long ba = __ballot(fa);
    unsigned long long bb = __ballot(fb);
    if (t == 0) { ws[0] = ba ? 1 : 0; ws[1] = bb ? 1 : 0; }
}

// Merged pack + W-prep: block < PACK_WBLK handles exactly one W row (1024
// packed dwords) — packs it AND computes rowsum + requant params inline.
// Blocks >= PACK_WBLK pack the A segment. Early-exit per segment when packed.
#define PACK_WBLK 4096   // = N_DIM rows
#define PACK_ABLK 8192   // = M*K/4/1024
__global__ __launch_bounds__(256)
void ql_pack2_kernel(const void* wsrc, int* wdst, const void* asrc, int* adst,
                     const int* qbias, const float* wscale, int* ws) {
    __shared__ int red[4];
    const int fA = __builtin_amdgcn_readfirstlane(ws[0]);
    const int fW = __builtin_amdgcn_readfirstlane(ws[1]);
    const int bid = blockIdx.x;
    const int tid = threadIdx.x;
    if (bid < PACK_WBLK) {
        if (fW) return;                      // W already int8; prep8 handles params
        const int n = bid;                   // W row index
        const int32x4* src = (const int32x4*)wsrc + (size_t)n * 1024;
        int* dst = wdst + (size_t)n * 1024;
        int s = 0;
#pragma unroll
        for (int k = 0; k < 4; ++k) {
            const int i = k * 256 + tid;
            int32x4 v = src[i];
            s += v.x + v.y + v.z + v.w;
            dst[i] = (v.x & 0xFF) | ((v.y & 0xFF) << 8) | ((v.z & 0xFF) << 16) | (v.w << 24);
        }
#pragma unroll
        for (int off = 32; off > 0; off >>= 1) s += __shfl_down(s, off, 64);
        if ((tid & 63) == 0) red[tid >> 6] = s;
        __syncthreads();
        if (tid == 0) {
            const int st = red[0] + red[1] + red[2] + red[3];
            ws[16 + n] = qbias[n] + 3 * st;                      // qbias - rowsum*Zin
            float folded = (0.05f * wscale[n]) / 0.1f;           // in (0,1)
            int fbits = (int)(7.0f - ceilf(log2f(folded)));
            int isc = (int)rintf(folded * exp2f((float)fbits));
            ws[16 + N_DIM + n] = isc;
            ws[16 + 2 * N_DIM + n] = fbits;
        }
    } else {
        if (fA) return;
        const long base = (long)(bid - PACK_WBLK) * 1024;
        const int32x4* src = (const int32x4*)asrc + base;
        int* dst = adst + base;
#pragma unroll
        for (int k = 0; k < 4; ++k) {
            const int i = k * 256 + tid;
            int32x4 v = src[i];
            dst[i] = (v.x & 0xFF) | ((v.y & 0xFF) << 8) | ((v.z & 0xFF) << 16) | (v.w << 24);
        }
    }
}

// Fast-path prep: only needed when W arrived already-packed int8.
__global__ void ql_prep8_kernel(const void* worig, const int* qbias,
                                const float* wscale, int* ws) {
    const int fb = __builtin_amdgcn_readfirstlane(ws[1]);
    if (!fb) return;                         // pack already wrote the params

    const int lane = threadIdx.x & 63;
    const int wid  = threadIdx.x >> 6;
    const int n = blockIdx.x * 4 + wid;

    const int32x4* row = (const int32x4*)((const int8_t*)worig + (size_t)n * K_DIM);
    int s = 0;
    for (int c = lane; c < K_DIM / 16; c += 64) {
        int32x4 v = row[c];
#pragma unroll
        for (int j = 0; j < 4; ++j) {
            int w = (j == 0) ? v.x : (j == 1) ? v.y : (j == 2) ? v.z : v.w;
            s += (int)(int8_t)(w) + (int)(int8_t)(w >> 8)
               + (int)(int8_t)(w >> 16) + (w >> 24);
        }
    }
#pragma unroll
    for (int off = 32; off > 0; off >>= 1) s += __shfl_down(s, off, 64);

    if (lane == 0) {
        ws[16 + n] = qbias[n] + 3 * s;                       // qbias - rowsum*Zin, Zin=-3
        float folded = (0.05f * wscale[n]) / 0.1f;           // in (0,1)
        int fbits = (int)(7.0f - ceilf(log2f(folded)));
        int isc = (int)rintf(folded * exp2f((float)fbits));  // nearest-even == np.round
        ws[16 + N_DIM + n] = isc;
        ws[16 + 2 * N_DIM + n] = fbits;
    }
}

// Fallback prep (ws too small): reads original W, flag-based.
__global__ void ql_prep_kernel(const void* wptr, const int* qbias,
                               const float* wscale, int* ws) {
    const int lane = threadIdx.x & 63;
    const int wid  = threadIdx.x >> 6;
    const int n = blockIdx.x * 4 + wid;
    const int b8 = __builtin_amdgcn_readfirstlane(ws[1]);

    int s = 0;
    if (b8) {
        const int32x4* row = (const int32x4*)((const int8_t*)wptr + (size_t)n * K_DIM);
        for (int c = lane; c < K_DIM / 16; c += 64) {
            int32x4 v = row[c];
#pragma unroll
            for (int j = 0; j < 4; ++j) {
                int w = (j == 0) ? v.x : (j == 1) ? v.y : (j == 2) ? v.z : v.w;
                s += (int)(int8_t)(w) + (int)(int8_t)(w >> 8)
                   + (int)(int8_t)(w >> 16) + (w >> 24);
            }
        }
    } else {
        const int32x4* row = (const int32x4*)((const int*)wptr + (size_t)n * K_DIM);
        for (int c = lane; c < K_DIM / 4; c += 64) {
            int32x4 v = row[c];
            s += v.x + v.y + v.z + v.w;
        }
    }
#pragma unroll
    for (int off = 32; off > 0; off >>= 1) s += __shfl_down(s, off, 64);

    if (lane == 0) {
        ws[16 + n] = qbias[n] + 3 * s;
        float folded = (0.05f * wscale[n]) / 0.1f;
        int fbits = (int)(7.0f - ceilf(log2f(folded)));
        int isc = (int)rintf(folded * exp2f((float)fbits));
        ws[16 + N_DIM + n] = isc;
        ws[16 + 2 * N_DIM + n] = fbits;
    }
}

// Fallback epilogue (128x128 path): requantize acc tile and store int32.
__device__ __forceinline__ void ql_epilogue(int32x4 acc[4][4], const int* ws,
                                            int* out, int bm, int bn,
                                            int wm, int wn, int qm, int qh) {
    const int* qb  = ws + 16;
    const int* isc = ws + 16 + N_DIM;
    const int* fbt = ws + 16 + 2 * N_DIM;
#pragma unroll
    for (int j = 0; j < 4; ++j) {
        const int n_g = bn * BN + wn + j * 16 + qm;
        const int b0 = qb[n_g];
        const int s0 = isc[n_g];
        const int f0 = fbt[n_g];
#pragma unroll
        for (int i = 0; i < 4; ++i) {
            const int m_base = bm * BM + wm + i * 16 + qh * 4;
#pragma unroll
            for (int r = 0; r < 4; ++r) {
                int v = ((r == 0) ? acc[i][j].x : (r == 1) ? acc[i][j].y
                        : (r == 2) ? acc[i][j].z : acc[i][j].w) + b0;
                long long p = (long long)v * (long long)s0;
                int o = (int)(p >> f0) - 5;            // + OUTPUT_ZERO_POINT (-5)
                o = o < -128 ? -128 : (o > 127 ? 127 : o);
                out[(size_t)(m_base + r) * N_DIM + n_g] = o;
            }
        }
    }
}

// ---- fast path: 256x256, 32x32x32 i8, R4 schedule + WAVE-PARITY ANTI-PHASE ----
// R4 (best measured, 135us/44.5% MfmaUtil): stage-early, ONE __syncthreads/tile.
// Diagnosis: all prior schedules lockstep 8 waves into read-burst then
// MFMA-burst -> LDS pipe (~4517cy) and matrix pipe (~4681cy) SERIALIZE
// (sum==measured 10125cy/tile-pair). Fix: no mid-tile barriers + opposite
// per-parity work order so ~half the waves read while the other half MFMA:
//   even waves: rd(A-lo,B0) -> q(0,0) -> rd(B1) -> q(0,1) -> rd(A-hi) -> q(1,0),q(1,1)
//   odd  waves: rd(A-hi,B1) -> q(1,1) -> rd(B0) -> q(1,0) -> rd(A-lo) -> q(0,0),q(0,1)
// Wave-uniform branch; integer accumulation order-independent (exact).
// LDS geometry: proven zero-conflict (R3/R4): phys = c ^ f(row),
// f(row) = (row&7) ^ ((row>>3)&3); stage source pre-applies f.

#define LOAD_AF(BUF, MH, DST) do { \
    _Pragma("unroll") for (int ml = 0; ml < 2; ++ml) \
    _Pragma("unroll") for (int kc = 0; kc < 4; ++kc) \
        DST[ml][kc] = LA[BUF][baseAe[kc] + (MH) * 512 + ml * 256]; \
} while (0)

#define LOAD_BF(BUF, NH, DST) do { \
    _Pragma("unroll") for (int kc = 0; kc < 4; ++kc) \
        DST[kc] = LB[BUF][baseBe[kc] + (NH) * 256]; \
} while (0)

#define MFMA_QUAD(MH, NH, AF, BF) do { \
    __builtin_amdgcn_s_setprio(1); \
    _Pragma("unroll") for (int kc = 0; kc < 4; ++kc) \
    _Pragma("unroll") for (int ml = 0; ml < 2; ++ml) \
        acc[(MH) * 2 + ml][NH] = __builtin_amdgcn_mfma_i32_32x32x32_i8( \
            AF[ml][kc], BF[kc], acc[(MH) * 2 + ml][NH], 0, 0, 0); \
    __builtin_amdgcn_s_setprio(0); \
} while (0)

#define STAGE8(BUF, TT) do { \
    _Pragma("unroll") for (int h2 = 0; h2 < 4; ++h2) { \
        async_copy16(gA + (size_t)(TT) * 128 + (size_t)h2 * 262144, \
                     &LA[BUF][h2 * 512 + t]); \
        async_copy16(gB + (size_t)(TT) * 128 + (size_t)h2 * 262144, \
                     &LB[BUF][h2 * 512 + t]); \
    } \
} while (0)

#define TILE2(BUF, TT) do { \
    if (evenw) { LOAD_AF(BUF, 0, afL); LOAD_BF(BUF, 0, bf0); } \
    else       { LOAD_AF(BUF, 1, afH); LOAD_BF(BUF, 1, bf1); } \
    if ((TT) + 1 < NKT) { STAGE8((BUF) ^ 1, (TT) + 1); } \
    if (evenw) { \
        MFMA_QUAD(0, 0, afL, bf0); \
        LOAD_BF(BUF, 1, bf1); \
        MFMA_QUAD(0, 1, afL, bf1); \
        LOAD_AF(BUF, 1, afH); \
        MFMA_QUAD(1, 0, afH, bf0); \
        MFMA_QUAD(1, 1, afH, bf1); \
    } else { \
        MFMA_QUAD(1, 1, afH, bf1); \
        LOAD_BF(BUF, 0, bf0); \
        MFMA_QUAD(1, 0, afH, bf0); \
        LOAD_AF(BUF, 0, afL); \
        MFMA_QUAD(0, 0, afL, bf0); \
        MFMA_QUAD(0, 1, afL, bf1); \
    } \
    __syncthreads(); \
} while (0)

__global__ __launch_bounds__(512, 2)
void ql_gemm8_kernel(const void* a0, const int8_t* a8,
                     const void* b0, const int8_t* w8,
                     const int* ws, int* out) {
    __shared__ int32x4 LA[2][2048];   // 2 x 32 KB
    __shared__ int32x4 LB[2][2048];   // total 128 KB

    const int fa = __builtin_amdgcn_readfirstlane(ws[0]);
    const int fb = __builtin_amdgcn_readfirstlane(ws[1]);
    const int8_t* aptr = fa ? (const int8_t*)a0 : a8;
    const int8_t* bptr = fb ? (const int8_t*)b0 : w8;

    const int t    = threadIdx.x;     // 512 threads = 8 waves
    const int lane = t & 63;
    const int wid  = t >> 6;          // 0..7
    const int wr   = wid >> 2;        // 0..1  M-half (128 rows)
    const int wc   = wid & 3;         // 0..3  N-quarter (64 cols)
    const int l31  = lane & 31;
    const int hi   = lane >> 5;
    const bool evenw = (wid & 1) == 0;

    // XCD-chunked bijective swizzle (nwg = 512 = 8 XCD x 64)
    const int flat = blockIdx.y * gridDim.x + blockIdx.x;   // 0..511
    const int xcd  = flat & 7;
    const int lid  = flat >> 3;
    const int g    = lid >> 5;
    const int r    = lid & 31;
    const int bm   = xcd * 4 + g * 2 + (r & 1);   // 0..31
    const int bn   = r >> 1;                      // 0..15

    const int arow0 = bm * BM2;
    const int brow0 = bn * BN2;

    // LDS frag bases (units of int32x4). phys = logical ^ f(row),
    // f(row) = (row&7) ^ ((row>>3)&3). All frag-row offsets are multiples of
    // 32 -> f = (lane&7) ^ ((l31>>3)&3) uniformly.
    const int fr = (lane & 7) ^ ((l31 >> 3) & 3);
    int baseAe[4], baseBe[4];
#pragma unroll
    for (int kc = 0; kc < 4; ++kc) {
        const int phys = (kc * 2 + hi) ^ fr;
        baseAe[kc] = (wr * 128 + l31) * 8 + phys;
        baseBe[kc] = (wc * 64  + l31) * 8 + phys;
    }

    // Stage source pre-swizzle: thread t writes phys chunk (t&7) of row
    // h2*64 + (t>>3); logical col = (t&7) ^ f(row) = (t&7)^((t>>3)&7)^((t>>6)&3).
    const int colg = (t & 7) ^ ((t >> 3) & 7) ^ ((t >> 6) & 3);
    const int8_t* gA = aptr + (size_t)(arow0 + (t >> 3)) * K_DIM + colg * 16;
    const int8_t* gB = bptr + (size_t)(brow0 + (t >> 3)) * K_DIM + colg * 16;

    int32x16 acc[4][2] = {};
    int32x4 afL[2][4], afH[2][4], bf0[4], bf1[4];

    // prologue: stage T0 -> buf0 (8 loads/thread)
    STAGE8(0, 0);
    __syncthreads();

#pragma unroll 1
    for (int T = 0; T < NKT; T += 2) {
        TILE2(0, T);
        TILE2(1, T + 1);
    }

    // epilogue: requantize + non-temporal store
    // (C/D map: col=lane&31, row=(reg&3)+8*(reg>>2)+4*hi)
    const int* qb  = ws + 16;
    const int* isc = ws + 16 + N_DIM;
    const int* fbt = ws + 16 + 2 * N_DIM;
#pragma unroll
    for (int j = 0; j < 2; ++j) {
        const int n_g = bn * BN2 + wc * 64 + j * 32 + l31;
        const int b0r = qb[n_g];
        const int s0r = isc[n_g];
        const int f0r = fbt[n_g];
#pragma unroll
        for (int i = 0; i < 4; ++i) {
            const int m0 = bm * BM2 + wr * 128 + i * 32 + hi * 4;
#pragma unroll
            for (int reg = 0; reg < 16; ++reg) {
                const int row = (reg & 3) + 8 * (reg >> 2);
                int v = acc[i][j][reg] + b0r;
                long long p = (long long)v * (long long)s0r;
                int o = (int)(p >> f0r) - 5;           // + OUTPUT_ZERO_POINT (-5)
                o = o < -128 ? -128 : (o > 127 ? 127 : o);
                __builtin_nontemporal_store(o, &out[(size_t)(m0 + row) * N_DIM + n_g]);
            }
        }
    }
}

// Fallback (ws too small): verified 128x128 kernel, packs in-loop.
__global__ __launch_bounds__(256)
void ql_gemm_fb_kernel(const void* aptr, const void* bptr, const int* ws, int* out) {
    __shared__ int32x4 Als[BM * BK / 16];
    __shared__ int32x4 Bls[BN * BK / 16];

    const int a8 = __builtin_amdgcn_readfirstlane(ws[0]);
    const int b8 = __builtin_amdgcn_readfirstlane(ws[1]);

    const int t    = threadIdx.x;
    const int lane = t & 63;
    const int wid  = t >> 6;
    const int bn = blockIdx.x;
    const int bm = blockIdx.y;

    const int wm = (wid >> 1) * 64;
    const int wn = (wid & 1) * 64;
    const int qm = lane & 15;
    const int qh = lane >> 4;

    int32x4 acc[4][4] = {};

    for (int kt = 0; kt < K_DIM / BK; ++kt) {
        __syncthreads();
        const int k0 = kt * BK;
#pragma unroll
        for (int r = 0; r < 4; ++r) {
            const int c    = r * 256 + t;
            const int row  = c >> 3;
            const int colg = (c & 7) ^ (row & 7);
            const size_t offA = (size_t)(bm * BM + row) * K_DIM + k0 + colg * 16;
            const size_t offB = (size_t)(bn * BN + row) * K_DIM + k0 + colg * 16;
            if (a8) async_copy16((const int8_t*)aptr + offA, &Als[c]);
            else    Als[c] = pack16((const int*)aptr + offA);
            if (b8) async_copy16((const int8_t*)bptr + offB, &Bls[c]);
            else    Bls[c] = pack16((const int*)bptr + offB);
        }
        __syncthreads();

#pragma unroll
        for (int s = 0; s < 2; ++s) {
            const int colk = s * 4 + qh;
            int32x4 af[4], bf[4];
#pragma unroll
            for (int i = 0; i < 4; ++i) {
                const int ra = wm + i * 16 + qm;
                const int rb = wn + i * 16 + qm;
                af[i] = Als[ra * 8 + (colk ^ (ra & 7))];
                bf[i] = Bls[rb * 8 + (colk ^ (rb & 7))];
            }
#pragma unroll
            for (int i = 0; i < 4; ++i)
#pragma unroll
                for (int j = 0; j < 4; ++j)
                    acc[i][j] = __builtin_amdgcn_mfma_i32_16x16x64_i8(
                        af[i], bf[j], acc[i][j], 0, 0, 0);
        }
    }
    ql_epilogue(acc, ws, out, bm, bn, wm, wn, qm, qh);
}

extern "C" void kernel_launch(void* const* d_in, const int* in_sizes, int n_in,
                              void* d_out, int out_size, void* d_ws, size_t ws_size,
                              hipStream_t stream) {
    const void* qin    = d_in[0];
    const void* qwt    = d_in[1];
    const int* qbias   = (const int*)d_in[2];
    const float* wscal = (const float*)d_in[3];
    int* ws  = (int*)d_ws;
    int* out = (int*)d_out;

    hipLaunchKernelGGL(ql_detect_kernel, dim3(1), dim3(64), 0, stream,
                       (const int*)qin, (const int*)qwt, ws);

    const size_t need = 65536 + (size_t)M_DIM * K_DIM + (size_t)N_DIM * K_DIM;
    if (ws_size >= need) {
        int8_t* a8 = (int8_t*)d_ws + 65536;
        int8_t* w8 = a8 + (size_t)M_DIM * K_DIM;
        hipLaunchKernelGGL(ql_pack2_kernel, dim3(PACK_WBLK + PACK_ABLK), dim3(256),
                           0, stream, qwt, (int*)w8, qin, (int*)a8, qbias, wscal, ws);
        hipLaunchKernelGGL(ql_prep8_kernel, dim3(N_DIM / 4), dim3(256), 0, stream,
                           qwt, qbias, wscal, ws);
        hipLaunchKernelGGL(ql_gemm8_kernel, dim3(N_DIM / BN2, M_DIM / BM2), dim3(512),
                           0, stream, qin, a8, qwt, w8, ws, out);
    } else {
        hipLaunchKernelGGL(ql_prep_kernel, dim3(N_DIM / 4), dim3(256), 0, stream,
                           qwt, qbias, wscal, ws);
        hipLaunchKernelGGL(ql_gemm_fb_kernel, dim3(N_DIM / BN, M_DIM / BM), dim3(256), 0, stream,
                           qin, qwt, ws, out);
    }
}